// Round 7
// baseline (233.915 us; speedup 1.0000x reference)
//
#include <hip/hip_runtime.h>

// ---- types ----
typedef __attribute__((ext_vector_type(8))) short bf16x8;   // 8 bf16 (4 VGPR)
typedef __attribute__((ext_vector_type(4))) short s16x4;
typedef __attribute__((ext_vector_type(8))) short s16x8;
typedef __attribute__((ext_vector_type(4))) float fx4;
typedef __attribute__((ext_vector_type(2))) unsigned int u32x2;

static __device__ __forceinline__ short f2bf(float f) {
  unsigned u = __builtin_bit_cast(unsigned, f);
  u += 0x7fffu + ((u >> 16) & 1u);          // RNE
  return (short)(u >> 16);
}

static __device__ __forceinline__ void gload_lds16(const void* g, void* l) {
  __builtin_amdgcn_global_load_lds(
      (const __attribute__((address_space(1))) unsigned int*)g,
      (__attribute__((address_space(3))) unsigned int*)l, 16, 0, 0);
}

// Problem constants
#define BB_ 2
#define SS_ 2048
#define DD_ 1024
#define HH_ 16
#define HD_ 64

// ---------------------------------------------------------------------------
// Kernel 1: fp32 -> bf16 convert (unchanged from R6)
// ---------------------------------------------------------------------------
__global__ __launch_bounds__(256) void cvt_kernel(
    const float* __restrict__ q, const float* __restrict__ k, const float* __restrict__ v,
    const float* __restrict__ Wq, const float* __restrict__ Wk, const float* __restrict__ Wv,
    const float* __restrict__ Wo,
    short* __restrict__ xq, short* __restrict__ xk, short* __restrict__ xv,
    short* __restrict__ wq, short* __restrict__ wk, short* __restrict__ wv,
    short* __restrict__ wo) {
  size_t e = ((size_t)blockIdx.x * 256 + threadIdx.x) * 8;
  const float* src; short* dst; size_t off;
  if (e < 4194304u)        { src = q;  dst = xq; off = e; }
  else if (e < 8388608u)   { src = k;  dst = xk; off = e - 4194304u; }
  else if (e < 12582912u)  { src = v;  dst = xv; off = e - 8388608u; }
  else if (e < 13631488u)  { src = Wq; dst = wq; off = e - 12582912u; }
  else if (e < 14680064u)  { src = Wk; dst = wk; off = e - 13631488u; }
  else if (e < 15728640u)  { src = Wv; dst = wv; off = e - 14680064u; }
  else                     { src = Wo; dst = wo; off = e - 15728640u; }
  fx4 a = *(const fx4*)(src + off);
  fx4 b = *(const fx4*)(src + off + 4);
  s16x8 o;
  o[0] = f2bf(a[0]); o[1] = f2bf(a[1]); o[2] = f2bf(a[2]); o[3] = f2bf(a[3]);
  o[4] = f2bf(b[0]); o[5] = f2bf(b[1]); o[6] = f2bf(b[2]); o[7] = f2bf(b[3]);
  *(s16x8*)(dst + off) = o;
}

// ---------------------------------------------------------------------------
// Kernel 2: QKV projection GEMM (unchanged from R6)
// ---------------------------------------------------------------------------
__global__ __launch_bounds__(256) void proj_gemm(
    const short* __restrict__ xq, const short* __restrict__ xk, const short* __restrict__ xv,
    const short* __restrict__ wq, const short* __restrict__ wk, const short* __restrict__ wv,
    const float* __restrict__ bq, const float* __restrict__ bk, const float* __restrict__ bv,
    short* __restrict__ qout, short* __restrict__ kout, short* __restrict__ vtout) {
  constexpr int K = DD_;
  __shared__ short As[2][128 * 32];
  __shared__ short Bs[2][128 * 32];
  int z = blockIdx.z;
  const short* A = (z == 0) ? xq : ((z == 1) ? xk : xv);
  const short* W = (z == 0) ? wq : ((z == 1) ? wk : wv);
  const float* bias = (z == 0) ? bq : ((z == 1) ? bk : bv);
  int m0 = blockIdx.x * 128, n0 = blockIdx.y * 128;
  int tid = threadIdx.x, lane = tid & 63, wv_ = tid >> 6;
  int wr = wv_ >> 1, wc = wv_ & 1;
  int c = lane & 15, g = lane >> 4;
  fx4 acc[4][4] = {};

  const char* Ab = (const char*)A + (size_t)m0 * K * 2;
  const char* Wb = (const char*)W + (size_t)n0 * K * 2;
  int o0 = tid * 16, o1 = (256 + tid) * 16;          // 2 x 4KB = 8KB tile
  size_t aoff0 = (size_t)(o0 >> 6) * (K * 2) + (o0 & 63);
  size_t aoff1 = (size_t)(o1 >> 6) * (K * 2) + (o1 & 63);

  gload_lds16(Ab + aoff0, ((char*)As[0]) + o0);
  gload_lds16(Ab + aoff1, ((char*)As[0]) + o1);
  gload_lds16(Wb + aoff0, ((char*)Bs[0]) + o0);
  gload_lds16(Wb + aoff1, ((char*)Bs[0]) + o1);
  __syncthreads();

  for (int k0 = 0; k0 < K; k0 += 32) {
    int cur = (k0 >> 5) & 1;
    if (k0 + 32 < K) {
      size_t kb2 = (size_t)(k0 + 32) * 2;
      gload_lds16(Ab + aoff0 + kb2, ((char*)As[cur ^ 1]) + o0);
      gload_lds16(Ab + aoff1 + kb2, ((char*)As[cur ^ 1]) + o1);
      gload_lds16(Wb + aoff0 + kb2, ((char*)Bs[cur ^ 1]) + o0);
      gload_lds16(Wb + aoff1 + kb2, ((char*)Bs[cur ^ 1]) + o1);
    }
    bf16x8 a[4], b[4];
#pragma unroll
    for (int i = 0; i < 4; i++) a[i] = *(const bf16x8*)(As[cur] + (wr * 64 + i * 16 + c) * 32 + g * 8);
#pragma unroll
    for (int j = 0; j < 4; j++) b[j] = *(const bf16x8*)(Bs[cur] + (wc * 64 + j * 16 + c) * 32 + g * 8);
#pragma unroll
    for (int i = 0; i < 4; i++)
#pragma unroll
      for (int j = 0; j < 4; j++)
        acc[i][j] = __builtin_amdgcn_mfma_f32_16x16x32_bf16(a[i], b[j], acc[i][j], 0, 0, 0);
    __syncthreads();
  }

#pragma unroll
  for (int i = 0; i < 4; i++)
#pragma unroll
    for (int j = 0; j < 4; j++) {
      int gcol = n0 + wc * 64 + j * 16 + c;
      float bv_ = bias[gcol];
      int hh = gcol >> 6, hd = gcol & 63;
      if (z == 2) {
        int grow0 = m0 + wr * 64 + i * 16 + g * 4;
        int bb2 = grow0 >> 11, s0 = grow0 & 2047;
        s16x4 pk;
#pragma unroll
        for (int r = 0; r < 4; r++) pk[r] = f2bf(acc[i][j][r] + bv_);
        *(s16x4*)(vtout + ((size_t)((bb2 * HH_ + hh) * HD_ + hd) * SS_ + s0)) = pk;
      } else {
#pragma unroll
        for (int r = 0; r < 4; r++) {
          int grow = m0 + wr * 64 + i * 16 + g * 4 + r;
          int bb2 = grow >> 11, s = grow & 2047;
          float val = acc[i][j][r] + bv_;
          size_t idx = ((size_t)(bb2 * HH_ + hh) * SS_ + s) * HD_ + hd;
          // fold scale (1/8) AND log2(e) into Q -> QK^T output is base-2
          if (z == 0) qout[idx] = f2bf(val * 0.1803368801f);
          else        kout[idx] = f2bf(val);
        }
      }
    }
}

// ---------------------------------------------------------------------------
// Kernel 3: flash attention R7: 2 waves x 32 q-rows (128 threads) -- K/V
// fragments read ONCE per tt/n and reused across 2 q-groups (halves LDS
// bytes/FLOP). Fixed-max softmax, v_perm pack, MFMA-ones l. LDS 40960.
// ---------------------------------------------------------------------------
__global__ __launch_bounds__(128) void attn_kernel(
    const short* __restrict__ qb, const short* __restrict__ kb, const short* __restrict__ vt,
    const int* __restrict__ mask, short* __restrict__ aout) {
  __shared__ char Ksh[2][8192];      // K tile [64 kv][64 hd] bf16, chunk-XOR swizzled
  __shared__ char Vsh[2][8192];      // V^T tile [64 hd][64 kv] bf16, chunk-XOR swizzled
  __shared__ char Plds[2][4096];     // per-wave P [32 q][64 kv] bf16, chunk-XOR swizzled

  int L = blockIdx.x;
  int W = (L & 7) * 128 + (L >> 3);  // XCD-contiguous chunks
  int qblk = W & 31, h = (W >> 5) & 15, b = W >> 9;

  int tid = threadIdx.x, lane = tid & 63, w = tid >> 6;   // w in {0,1}
  int c = lane & 15, g = lane >> 4;

  const char* Kp = (const char*)(kb + (size_t)(b * HH_ + h) * SS_ * HD_);
  const char* Vp = (const char*)(vt + (size_t)(b * HH_ + h) * HD_ * SS_);

  // staging: LDS[row][chunk] = Global[row][chunk ^ (row&7)] (16B chunks)
  // 2 waves x 4 instrs each cover the 8KB tile (8 x 1KB wave-instrs)
  int r8 = lane >> 3, c8 = lane & 7;
  int swz = (c8 ^ r8) * 16;
  int kOff[4], vOff[4], ldst[4];
#pragma unroll
  for (int j = 0; j < 4; j++) {
    int i = w * 4 + j;
    kOff[j] = (i * 8 + r8) * 128 + swz;
    vOff[j] = (i * 8 + r8) * 4096 + swz;
    ldst[j] = i * 1024;
  }
#pragma unroll
  for (int j = 0; j < 4; j++) gload_lds16(Kp + kOff[j], &Ksh[0][ldst[j]]);
#pragma unroll
  for (int j = 0; j < 4; j++) gload_lds16(Vp + vOff[j], &Vsh[0][ldst[j]]);

  // per-wave len scan (mask monotone: masked iff i >= len); identical in waves
  int lmin = SS_;
  for (int i = lane; i < SS_; i += 64)
    if (mask[b * SS_ + i] && i < lmin) lmin = i;
#pragma unroll
  for (int off = 32; off >= 1; off >>= 1) {
    int o2 = __shfl_xor(lmin, off);
    lmin = (o2 < lmin) ? o2 : lmin;
  }
  int len = lmin;                       // block-uniform
  int nt = (len + 63) >> 6;
  float lenf = (float)len;

  __syncthreads();                      // tile-0 staging drained

  int q0w = qblk * 64 + w * 32;         // this wave's 32 q-rows
  const short* Qp = qb + (size_t)(b * HH_ + h) * SS_ * HD_;
  bf16x8 aq[2][2];
#pragma unroll
  for (int qg = 0; qg < 2; qg++) {
    aq[qg][0] = *(const bf16x8*)(Qp + (q0w + qg * 16 + c) * HD_ + g * 8);
    aq[qg][1] = *(const bf16x8*)(Qp + (q0w + qg * 16 + c) * HD_ + 32 + g * 8);
  }
  fx4 o[2][4] = {};
  fx4 o5[2] = {};                       // l accumulators (MFMA-ones row-sum)
  float qf0 = (float)(q0w + c);
  char* Pw = Plds[w];
  const float NB = -0.144269504f;       // -0.1 * log2(e); QK out already base-2
  int cs = c & 7;
  int rc0 = (g ^ cs) * 16;
  int rc1 = ((4 + g) ^ cs) * 16;
  bf16x8 vones;
#pragma unroll
  for (int i = 0; i < 8; i++) vones[i] = (short)0x3F80;  // 1.0 bf16

  for (int t = 0; t < nt; ++t) {
    int cur = t & 1;
    if (t + 1 < nt) {
      const char* kpp = Kp + (t + 1) * 8192;   // 64 rows * 128B
      const char* vpp = Vp + (t + 1) * 128;    // 64 kv * 2B
#pragma unroll
      for (int j = 0; j < 4; j++) gload_lds16(kpp + kOff[j], &Ksh[cur ^ 1][ldst[j]]);
#pragma unroll
      for (int j = 0; j < 4; j++) gload_lds16(vpp + vOff[j], &Vsh[cur ^ 1][ldst[j]]);
    }
    const char* Kc = Ksh[cur];
    const char* Vc = Vsh[cur];

    // QK^T (swapped): s[qg][tt] lane (c,g) elem r = S_b2[kv=tt*16+g*4+r][q=qg*16+c]
    // ak fragments read once, reused across both q-groups.
    fx4 s[2][4];
    __builtin_amdgcn_s_setprio(1);
#pragma unroll
    for (int tt = 0; tt < 4; tt++) {
      bf16x8 ak0 = *(const bf16x8*)(Kc + (tt * 16 + c) * 128 + rc0);
      bf16x8 ak1 = *(const bf16x8*)(Kc + (tt * 16 + c) * 128 + rc1);
#pragma unroll
      for (int qg = 0; qg < 2; qg++) {
        fx4 z4 = {};
        s[qg][tt] = __builtin_amdgcn_mfma_f32_16x16x32_bf16(ak0, aq[qg][0], z4, 0, 0, 0);
        s[qg][tt] = __builtin_amdgcn_mfma_f32_16x16x32_bf16(ak1, aq[qg][1], s[qg][tt], 0, 0, 0);
      }
    }
    __builtin_amdgcn_s_setprio(0);

    // softmax (fixed M=0) + pack, per q-group
#pragma unroll
    for (int qg = 0; qg < 2; qg++) {
      float p[16];
      float dq = (qf0 + (float)(qg * 16)) - (float)(t * 64 + g * 4);
#pragma unroll
      for (int tt = 0; tt < 4; tt++)
#pragma unroll
        for (int r = 0; r < 4; r++)
          p[tt * 4 + r] = fmaf(NB, fabsf(dq - (float)(tt * 16 + r)), s[qg][tt][r]);
      if (t == nt - 1) {                // only last tile can have masked keys
        float kvb = (float)(t * 64 + g * 4);
#pragma unroll
        for (int tt = 0; tt < 4; tt++)
#pragma unroll
          for (int r = 0; r < 4; r++)
            if (kvb + (float)(tt * 16 + r) >= lenf) p[tt * 4 + r] = -1e30f;
      }
#pragma unroll
      for (int i = 0; i < 16; i++) p[i] = __builtin_amdgcn_exp2f(p[i]);

      // pack P to bf16 via v_perm truncation; P row = qg*16+c (row&7 == c&7)
#pragma unroll
      for (int tt = 0; tt < 4; tt++) {
        u32x2 pk2;
        pk2[0] = __builtin_amdgcn_perm(__builtin_bit_cast(unsigned, p[tt * 4 + 1]),
                                       __builtin_bit_cast(unsigned, p[tt * 4 + 0]), 0x07060302u);
        pk2[1] = __builtin_amdgcn_perm(__builtin_bit_cast(unsigned, p[tt * 4 + 3]),
                                       __builtin_bit_cast(unsigned, p[tt * 4 + 2]), 0x07060302u);
        *(u32x2*)(Pw + (qg * 16 + c) * 128 + ((2 * tt + (g >> 1)) ^ cs) * 16 + (g & 1) * 8) = pk2;
      }
    }

    bf16x8 pa[2][2];
#pragma unroll
    for (int qg = 0; qg < 2; qg++) {
      pa[qg][0] = *(const bf16x8*)(Pw + (qg * 16 + c) * 128 + rc0);
      pa[qg][1] = *(const bf16x8*)(Pw + (qg * 16 + c) * 128 + rc1);
    }
    __builtin_amdgcn_s_setprio(1);
#pragma unroll
    for (int n = 0; n < 4; n++) {
      bf16x8 v0 = *(const bf16x8*)(Vc + (n * 16 + c) * 128 + rc0);
      bf16x8 v1 = *(const bf16x8*)(Vc + (n * 16 + c) * 128 + rc1);
#pragma unroll
      for (int qg = 0; qg < 2; qg++) {
        o[qg][n] = __builtin_amdgcn_mfma_f32_16x16x32_bf16(pa[qg][0], v0, o[qg][n], 0, 0, 0);
        o[qg][n] = __builtin_amdgcn_mfma_f32_16x16x32_bf16(pa[qg][1], v1, o[qg][n], 0, 0, 0);
      }
    }
#pragma unroll
    for (int qg = 0; qg < 2; qg++) {
      o5[qg] = __builtin_amdgcn_mfma_f32_16x16x32_bf16(pa[qg][0], vones, o5[qg], 0, 0, 0);
      o5[qg] = __builtin_amdgcn_mfma_f32_16x16x32_bf16(pa[qg][1], vones, o5[qg], 0, 0, 0);
    }
    __builtin_amdgcn_s_setprio(0);

    __syncthreads();   // next tile staged + both waves done with cur
  }

#pragma unroll
  for (int qg = 0; qg < 2; qg++) {
    float linv[4];
#pragma unroll
    for (int r = 0; r < 4; r++) linv[r] = 1.0f / o5[qg][r];
#pragma unroll
    for (int n = 0; n < 4; n++)
#pragma unroll
      for (int r = 0; r < 4; r++) {
        int qrow = q0w + qg * 16 + g * 4 + r;
        float val = o[qg][n][r] * linv[r];
        aout[((size_t)(b * SS_ + qrow)) * DD_ + h * HD_ + n * 16 + c] = f2bf(val);
      }
  }
}

// ---------------------------------------------------------------------------
// Kernel 4: output projection R7: 64x128 tile (grid 512 -> 2 blocks/CU),
// 4 waves 2x2 (32x64 each), 2-phase dbuf, fp32 out.
// ---------------------------------------------------------------------------
__global__ __launch_bounds__(256) void oproj_gemm(
    const short* __restrict__ A, const short* __restrict__ W,
    const float* __restrict__ bias, float* __restrict__ out) {
  constexpr int K = DD_;
  __shared__ short As[2][64 * 32];     // 4KB each
  __shared__ short Bs[2][128 * 32];    // 8KB each
  int m0 = blockIdx.x * 64, n0 = blockIdx.y * 128;
  int tid = threadIdx.x, lane = tid & 63, wv_ = tid >> 6;
  int wr = wv_ >> 1, wc = wv_ & 1;
  int c = lane & 15, g = lane >> 4;
  fx4 acc[2][4] = {};
  const char* Ab = (const char*)A + (size_t)m0 * K * 2;
  const char* Wb = (const char*)W + (size_t)n0 * K * 2;
  int oA = tid * 16;                                  // A: 4KB, rows 0..63
  int oB0 = tid * 16, oB1 = (256 + tid) * 16;         // B: 8KB, rows 0..127
  size_t aoffA = (size_t)(oA >> 6) * (K * 2) + (oA & 63);
  size_t boff0 = (size_t)(oB0 >> 6) * (K * 2) + (oB0 & 63);
  size_t boff1 = (size_t)(oB1 >> 6) * (K * 2) + (oB1 & 63);

  gload_lds16(Ab + aoffA, ((char*)As[0]) + oA);
  gload_lds16(Wb + boff0, ((char*)Bs[0]) + oB0);
  gload_lds16(Wb + boff1, ((char*)Bs[0]) + oB1);
  __syncthreads();

  for (int k0 = 0; k0 < K; k0 += 32) {
    int cur = (k0 >> 5) & 1;
    if (k0 + 32 < K) {
      size_t kb2 = (size_t)(k0 + 32) * 2;
      gload_lds16(Ab + aoffA + kb2, ((char*)As[cur ^ 1]) + oA);
      gload_lds16(Wb + boff0 + kb2, ((char*)Bs[cur ^ 1]) + oB0);
      gload_lds16(Wb + boff1 + kb2, ((char*)Bs[cur ^ 1]) + oB1);
    }
    bf16x8 a[2], b[4];
#pragma unroll
    for (int i = 0; i < 2; i++) a[i] = *(const bf16x8*)(As[cur] + (wr * 32 + i * 16 + c) * 32 + g * 8);
#pragma unroll
    for (int j = 0; j < 4; j++) b[j] = *(const bf16x8*)(Bs[cur] + (wc * 64 + j * 16 + c) * 32 + g * 8);
#pragma unroll
    for (int i = 0; i < 2; i++)
#pragma unroll
      for (int j = 0; j < 4; j++)
        acc[i][j] = __builtin_amdgcn_mfma_f32_16x16x32_bf16(a[i], b[j], acc[i][j], 0, 0, 0);
    __syncthreads();
  }

#pragma unroll
  for (int i = 0; i < 2; i++)
#pragma unroll
    for (int j = 0; j < 4; j++) {
      int gcol = n0 + wc * 64 + j * 16 + c;
      float bv_ = bias[gcol];
#pragma unroll
      for (int r = 0; r < 4; r++) {
        int grow = m0 + wr * 32 + i * 16 + g * 4 + r;
        out[(size_t)grow * DD_ + gcol] = acc[i][j][r] + bv_;
      }
    }
}

// ---------------------------------------------------------------------------
extern "C" void kernel_launch(void* const* d_in, const int* in_sizes, int n_in,
                              void* d_out, int out_size, void* d_ws, size_t ws_size,
                              hipStream_t stream) {
  const float* q  = (const float*)d_in[0];
  const float* k  = (const float*)d_in[1];
  const float* v  = (const float*)d_in[2];
  const int* mask = (const int*)d_in[3];
  const float* Wq = (const float*)d_in[4];
  const float* bq = (const float*)d_in[5];
  const float* Wk = (const float*)d_in[6];
  const float* bk = (const float*)d_in[7];
  const float* Wv = (const float*)d_in[8];
  const float* bv = (const float*)d_in[9];
  const float* Wo = (const float*)d_in[10];
  const float* bo = (const float*)d_in[11];

  char* ws = (char*)d_ws;
  short* qbuf = (short*)(ws);                       // [B,H,S,HD] bf16, q*0.125*log2e
  short* kbuf = (short*)(ws + (8ull << 20));        // [B,H,S,HD]
  short* vtb  = (short*)(ws + (16ull << 20));       // [B,H,HD,S]
  short* abuf = (short*)(ws + (24ull << 20));       // [B,S,D] attention out bf16
  short* xq   = (short*)(ws + (32ull << 20));
  short* xk   = (short*)(ws + (40ull << 20));
  short* xv   = (short*)(ws + (48ull << 20));
  short* wq   = (short*)(ws + (56ull << 20));
  short* wk   = (short*)(ws + (58ull << 20));
  short* wv   = (short*)(ws + (60ull << 20));
  short* wo   = (short*)(ws + (62ull << 20));
  float* out  = (float*)d_out;

  cvt_kernel<<<8192, 256, 0, stream>>>(q, k, v, Wq, Wk, Wv, Wo, xq, xk, xv, wq, wk, wv, wo);
  dim3 gp(32, 8, 3);
  proj_gemm<<<gp, 256, 0, stream>>>(xq, xk, xv, wq, wk, wv, bq, bk, bv, qbuf, kbuf, vtb);
  attn_kernel<<<1024, 128, 0, stream>>>(qbuf, kbuf, vtb, mask, abuf);
  dim3 go(64, 8, 1);
  oproj_gemm<<<go, 256, 0, stream>>>(abuf, wo, bo, out);
}